// Round 13
// baseline (1347.485 us; speedup 1.0000x reference)
//
#include <hip/hip_runtime.h>
#include <math.h>

#define B_ 8192
#define L_ 49
#define C_ 512
#define R_ 128

typedef short   bf16x8 __attribute__((ext_vector_type(8)));
typedef unsigned short u16x8 __attribute__((ext_vector_type(8)));
typedef float   f32x4  __attribute__((ext_vector_type(4)));

// ws layout (ushort elements) — ALL weights wave-fragment-contiguous
#define WS_LWF   0           // 65536
#define WS_WB3F  65536       // 36864
#define WS_WB5F  102400      // 102400
#define WS_GWF   204800      // 65536
#define WS_CWF   270336      // 65536
#define WS_WBYTES 671744     // bytes of weight region (335872 ushorts)

// shared memory layout (bytes), total 44304
#define SM_XB    0           // ush[49][256] swizzled, 25088
#define SM_XLB   25088       // ush[50][128] swizzled, 12800 | overlay P1/P2: maxb+sumf
#define SM_MAXB  25088       //   bf16 maxb[8][256] = 4096
#define SM_SUMF  29184       //   f32 sumf[8][256]  = 8192
#define SM_GA    37888       // bf16 ga[2][256] = 1024
#define SM_G     38912       // f32 g[2][128] = 1024
#define SM_CA    39936       // f32 ca[512] = 2048
#define SM_SPW   41984       // f32 spw[8][64] = 2048
#define SM_SP    44032       // f32[64]
#define SM_GDOT  44288       // f32[4]
#define SM_TOT   44304

__device__ __forceinline__ float bf2f(unsigned short u) {
    union { float f; unsigned int i; } v; v.i = ((unsigned int)u) << 16; return v.f;
}
__device__ __forceinline__ unsigned short f2bf(float f) {
    union { float f; unsigned int i; } v; v.f = f;
    unsigned int r = v.i + 0x7fffu + ((v.i >> 16) & 1u);
    return (unsigned short)(r >> 16);
}
__device__ __forceinline__ float star_relu(float x, float sc, float bi) {
    float r = fmaxf(x, 0.f);
    return sc * r * r + bi;
}
__device__ __forceinline__ float sigmoidf_(float x) {
    return 1.f / (1.f + __expf(-x));
}

// ---------------- pre-pass: convert + repack weights to fragment-contiguous bf16 ----------------
__global__ void cvt_weights(const float* __restrict__ lw, const float* __restrict__ w3,
                            const float* __restrict__ w5, const float* __restrict__ gw,
                            const float* __restrict__ cw, unsigned short* __restrict__ ws)
{
    int t = blockIdx.x * blockDim.x + threadIdx.x;
    int stride = gridDim.x * blockDim.x;
    for (int i = t; i < 65536; i += stride) {
        int j = i & 7, lane = (i >> 3) & 63, ks = (i >> 9) & 15, nt = i >> 13;
        int n = nt * 16 + (lane & 15);
        int k = ks * 32 + (lane >> 4) * 8 + j;
        ws[WS_LWF + i] = f2bf(lw[n * 512 + k]);
        ws[WS_GWF + i] = f2bf(gw[n * 512 + k]);
    }
    for (int i = t; i < 65536; i += stride) {
        int j = i & 7, c = (i >> 3) & 511, r8 = i >> 12;
        ws[WS_CWF + i] = f2bf(cw[c * 128 + r8 * 8 + j]);
    }
    for (int i = t; i < 36864; i += stride) {
        int j = i & 7, lane = (i >> 3) & 63, ks = (i >> 9) & 1, f = (i >> 10) & 3, tap = i >> 12;
        int oc = f * 16 + (lane & 15);
        int ic = ks * 32 + (lane >> 4) * 8 + j;
        ws[WS_WB3F + i] = f2bf(w3[(oc * 64 + ic) * 9 + tap]);
    }
    for (int i = t; i < 102400; i += stride) {
        int j = i & 7, lane = (i >> 3) & 63, ks = (i >> 9) & 1, f = (i >> 10) & 3, tap = i >> 12;
        int oc = f * 16 + (lane & 15);
        int ic = ks * 32 + (lane >> 4) * 8 + j;
        ws[WS_WB5F + i] = f2bf(w5[(oc * 64 + ic) * 25 + tap]);
    }
}

// ---------------- conv tap-GEMM body. Invalid taps read zeroed row 49. ----------------
template <int NTAP, int KD, int PAD, int COLBASE>
__device__ __forceinline__ void conv_mfma(const unsigned short* __restrict__ s_xlb,
                                          const unsigned short* __restrict__ wtbf,
                                          int m16, int kg, int ln, int f, f32x4 C[4])
{
    int lp_[4], i_[4], j_[4];
    #pragma unroll
    for (int mf = 0; mf < 4; ++mf) {
        lp_[mf] = mf * 16 + m16;
        i_[mf] = lp_[mf] / 7;
        j_[mf] = lp_[mf] % 7;
    }
    #pragma unroll
    for (int tap = 0; tap < NTAP; ++tap) {
        const int dy = tap / KD - PAD, dx = tap % KD - PAD;
        int lc[4];
        #pragma unroll
        for (int mf = 0; mf < 4; ++mf) {
            int ii = i_[mf] + dy, jj = j_[mf] + dx;
            bool v = (lp_[mf] < 49) & (ii >= 0) & (ii < 7) & (jj >= 0) & (jj < 7);
            lc[mf] = v ? (ii * 7 + jj) : 49;              // row 49 is all zeros
        }
        #pragma unroll
        for (int ks = 0; ks < 2; ++ks) {
            bf16x8 bb = *(const bf16x8*)(wtbf + ((tap * 4 + f) * 2 + ks) * 512 + ln * 8);
            #pragma unroll
            for (int mf = 0; mf < 4; ++mf) {
                int chunk = ((COLBASE >> 3) + ks * 4 + kg) ^ (lc[mf] & 7);
                bf16x8 a = *(const bf16x8*)&s_xlb[lc[mf] * 128 + chunk * 8];
                C[mf] = __builtin_amdgcn_mfma_f32_16x16x32_bf16(a, bb, C[mf], 0, 0, 0);
            }
        }
    }
}

// ---------------- shared body: computes gates; WRITE_OUT selects fused vs split ----------------
template <int WRITE_OUT>
__device__ __forceinline__ void mafn_body(const float* __restrict__ x,
                const float* __restrict__ b3, const float* __restrict__ b5,
                const float* __restrict__ cb, const float* __restrict__ sw,
                const float* __restrict__ sb, const float* __restrict__ ssc,
                const float* __restrict__ sbi,
                const unsigned short* __restrict__ ws,
                float* __restrict__ out,
                float* __restrict__ ca_out, float* __restrict__ sp_out)
{
    __shared__ __align__(16) unsigned char smem[SM_TOT];
    unsigned short* s_xb   = (unsigned short*)(smem + SM_XB);
    unsigned short* s_xlb  = (unsigned short*)(smem + SM_XLB);
    unsigned short* s_maxb = (unsigned short*)(smem + SM_MAXB);
    float*          s_sumf = (float*)(smem + SM_SUMF);
    unsigned short* s_ga   = (unsigned short*)(smem + SM_GA);
    float*          s_g    = (float*)(smem + SM_G);
    float*          s_ca   = (float*)(smem + SM_CA);
    float*          s_spw  = (float*)(smem + SM_SPW);
    float*          s_sp   = (float*)(smem + SM_SP);
    float*          s_gdot = (float*)(smem + SM_GDOT);

    const int b = blockIdx.x, t = threadIdx.x;
    const int wv = t >> 6, ln = t & 63;
    const int m16 = ln & 15, kg = ln >> 4;
    const float scale = ssc[0], sbias = sbi[0];

    const unsigned short* lwf  = ws + WS_LWF;
    const unsigned short* wb3f = ws + WS_WB3F;
    const unsigned short* wb5f = ws + WS_WB5F;
    const unsigned short* gwf  = ws + WS_GWF;
    const unsigned short* cwf  = ws + WS_CWF;

    f32x4 accA[4];
    f32x4 accG;
    {
        const f32x4 z = {0.f, 0.f, 0.f, 0.f};
        #pragma unroll
        for (int mf = 0; mf < 4; ++mf) accA[mf] = z;
        accG = z;
    }

    const int l0 = wv * 6;
    const int nl = (wv < 7) ? 6 : 7;

    #pragma unroll 1
    for (int h = 0; h < 2; ++h) {
        // ---- P1 ----
        {
            const float4* x4 = (const float4*)(x + (size_t)b * (L_ * C_)) + h * 64;
            float4 mx = {-3.4e38f, -3.4e38f, -3.4e38f, -3.4e38f};
            float4 sm = {0.f, 0.f, 0.f, 0.f};
            for (int li = 0; li < nl; ++li) {
                int l = l0 + li;
                float4 v = x4[l * 128 + ln];
                mx.x = fmaxf(mx.x, v.x); mx.y = fmaxf(mx.y, v.y);
                mx.z = fmaxf(mx.z, v.z); mx.w = fmaxf(mx.w, v.w);
                sm.x += v.x; sm.y += v.y; sm.z += v.z; sm.w += v.w;
                ushort4 p;
                p.x = f2bf(v.x); p.y = f2bf(v.y); p.z = f2bf(v.z); p.w = f2bf(v.w);
                int chunk = (ln >> 1) ^ (l & 7);
                *(ushort4*)&s_xb[l * 256 + chunk * 8 + (ln & 1) * 4] = p;
            }
            ushort4 pm;
            pm.x = f2bf(mx.x); pm.y = f2bf(mx.y); pm.z = f2bf(mx.z); pm.w = f2bf(mx.w);
            *(ushort4*)&s_maxb[wv * 256 + ln * 4] = pm;
            *(float4*)&s_sumf[wv * 256 + ln * 4] = sm;
        }
        __syncthreads();

        // ---- P2 ----
        {
            if (t < 256) {
                int c = t;
                float m = bf2f(s_maxb[c]);
                #pragma unroll
                for (int i = 1; i < 8; ++i) m = fmaxf(m, bf2f(s_maxb[i * 256 + c]));
                s_ga[c] = f2bf(m);
            } else {
                int c = t - 256;
                float s = 0.f;
                #pragma unroll
                for (int i = 0; i < 8; ++i) s += s_sumf[i * 256 + c];
                s_ga[256 + c] = f2bf(s * (1.f / 49.f));
            }
        }
        __syncthreads();

        // ---- P3 ----
        {
            int rowA[4];
            #pragma unroll
            for (int mf = 0; mf < 4; ++mf) rowA[mf] = min(mf * 16 + m16, 48);
            #pragma unroll 2
            for (int ks = 0; ks < 8; ++ks) {
                bf16x8 bb = *(const bf16x8*)(lwf + (wv * 16 + h * 8 + ks) * 512 + ln * 8);
                #pragma unroll
                for (int mf = 0; mf < 4; ++mf) {
                    int chunk = (ks * 4 + kg) ^ (rowA[mf] & 7);
                    bf16x8 a = *(const bf16x8*)&s_xb[rowA[mf] * 256 + chunk * 8];
                    accA[mf] = __builtin_amdgcn_mfma_f32_16x16x32_bf16(a, bb, accA[mf], 0, 0, 0);
                }
            }
            const bf16x8 zz = {0,0,0,0,0,0,0,0};
            #pragma unroll 4
            for (int ks = 0; ks < 8; ++ks) {
                bf16x8 a = (m16 < 2) ? *(const bf16x8*)&s_ga[m16 * 256 + ks * 32 + kg * 8] : zz;
                bf16x8 bb = *(const bf16x8*)(gwf + (wv * 16 + h * 8 + ks) * 512 + ln * 8);
                accG = __builtin_amdgcn_mfma_f32_16x16x32_bf16(a, bb, accG, 0, 0, 0);
            }
        }
        __syncthreads();
    }

    // ---- P4 ----
    {
        if (t < 64) ((unsigned int*)(s_xlb + 49 * 128))[t] = 0;
        const int n = wv * 16 + m16;
        #pragma unroll
        for (int mf = 0; mf < 4; ++mf) {
            #pragma unroll
            for (int rg = 0; rg < 4; ++rg) {
                int lp = mf * 16 + kg * 4 + rg;
                if (lp < 49) {
                    int idx = lp * 128 + ((((n >> 3) ^ (lp & 7)) << 3) + (n & 7));
                    s_xlb[idx] = f2bf(accA[mf][rg]);
                }
            }
        }
        if (kg == 0) {
            s_g[n]       = star_relu(accG[0], scale, sbias);
            s_g[128 + n] = star_relu(accG[1], scale, sbias);
        }
    }
    __syncthreads();

    // ---- P5 ----
    const int f_ = wv & 3;
    const int oc_ = f_ * 16 + m16;
    {
        f32x4 C[4];
        const f32x4 z = {0.f, 0.f, 0.f, 0.f};
        #pragma unroll
        for (int mf = 0; mf < 4; ++mf) C[mf] = z;

        if (wv < 4) {
            conv_mfma<25, 5, 2, 64>(s_xlb, wb5f, m16, kg, ln, f_, C);
        } else {
            conv_mfma< 9, 3, 1,  0>(s_xlb, wb3f, m16, kg, ln, f_, C);
            const int idx = t - 256;
            #pragma unroll
            for (int half = 0; half < 2; ++half) {
                int c = idx + half * 256;
                float a0 = 0.f, a1 = 0.f;
                #pragma unroll 4
                for (int r8 = 0; r8 < 16; ++r8) {
                    u16x8 w = *(const u16x8*)(cwf + r8 * 4096 + c * 8);
                    float p = 0.f;
                    #pragma unroll
                    for (int k = 0; k < 8; ++k)
                        p += bf2f(w[k]) * (s_g[r8 * 8 + k] + s_g[128 + r8 * 8 + k]);
                    if (r8 & 1) a1 += p; else a0 += p;
                }
                s_ca[c] = sigmoidf_(a0 + a1 + 2.f * cb[c]);
            }
            if (wv == 7) {
                float p = s_g[ln] * sw[128 + ln] + s_g[128 + ln] * sw[256 + ln]
                        + s_g[ln + 64] * sw[128 + ln + 64] + s_g[128 + ln + 64] * sw[256 + ln + 64];
                #pragma unroll
                for (int off = 32; off > 0; off >>= 1) p += __shfl_xor(p, off);
                if (ln == 0) s_gdot[0] = p;
            }
        }

        const bool is5 = (wv < 4);
        const int ch = is5 ? 64 + oc_ : oc_;
        const float bias = is5 ? b5[oc_] : b3[oc_];
        const float sww = sw[ch];
        #pragma unroll
        for (int mf = 0; mf < 4; ++mf) {
            #pragma unroll
            for (int rg = 0; rg < 4; ++rg) {
                int lp = mf * 16 + kg * 4 + rg;
                float v = (lp < 49) ? star_relu(C[mf][rg] + bias, scale, sbias) * sww : 0.f;
                v += __shfl_xor(v, 1);
                v += __shfl_xor(v, 2);
                v += __shfl_xor(v, 4);
                v += __shfl_xor(v, 8);
                if (m16 == 0 && lp < 49) s_spw[wv * 64 + lp] = v;
            }
        }
    }
    __syncthreads();

    // ---- P6 ----
    if (t < 49) {
        float s = s_gdot[0] + sb[0];
        #pragma unroll
        for (int w = 0; w < 8; ++w) s += s_spw[w * 64 + t];
        s_sp[t] = sigmoidf_(s);
    }
    __syncthreads();

    // ---- P7 (fused) or gate store (split) ----
    if (WRITE_OUT) {
        const float4* x4 = (const float4*)(x + (size_t)b * (L_ * C_));
        float4* o4 = (float4*)(out + (size_t)b * (L_ * C_));
        const float4* ca4 = (const float4*)s_ca;
        for (int i = t; i < 49 * 128; i += 512) {
            int l = i >> 7, c4 = i & 127;
            float4 xv = x4[i];
            float g = s_sp[l];
            float4 cv = ca4[c4];
            float4 ov;
            ov.x = xv.x * cv.x * g;
            ov.y = xv.y * cv.y * g;
            ov.z = xv.z * cv.z * g;
            ov.w = xv.w * cv.w * g;
            o4[i] = ov;
        }
    } else {
        if (t < 512) ca_out[(size_t)b * 512 + t] = s_ca[t];
        if (t < 49)  sp_out[(size_t)b * 64 + t] = s_sp[t];
    }
}

__global__ __launch_bounds__(512, 4)
void mafn_gates(const float* __restrict__ x,
                const float* __restrict__ b3, const float* __restrict__ b5,
                const float* __restrict__ cb, const float* __restrict__ sw,
                const float* __restrict__ sb, const float* __restrict__ ssc,
                const float* __restrict__ sbi,
                const unsigned short* __restrict__ ws,
                float* __restrict__ ca_out, float* __restrict__ sp_out)
{
    mafn_body<0>(x, b3, b5, cb, sw, sb, ssc, sbi, ws, nullptr, ca_out, sp_out);
}

__global__ __launch_bounds__(512, 4)
void mafn_fused(const float* __restrict__ x,
                const float* __restrict__ b3, const float* __restrict__ b5,
                const float* __restrict__ cb, const float* __restrict__ sw,
                const float* __restrict__ sb, const float* __restrict__ ssc,
                const float* __restrict__ sbi,
                const unsigned short* __restrict__ ws,
                float* __restrict__ out)
{
    mafn_body<1>(x, b3, b5, cb, sw, sb, ssc, sbi, ws, out, nullptr, nullptr);
}

// ---------------- streaming apply: out = x * ca[b][c] * sp[b][l] ----------------
__global__ __launch_bounds__(256)
void apply_gates(const float* __restrict__ x,
                 const float* __restrict__ ca, const float* __restrict__ sp,
                 float* __restrict__ out)
{
    const long long total = (long long)B_ * (L_ * C_ / 4);     // float4 units
    const int stride = gridDim.x * blockDim.x;
    const float4* x4 = (const float4*)x;
    float4* o4 = (float4*)out;
    for (long long i = blockIdx.x * blockDim.x + threadIdx.x; i < total; i += stride) {
        int b = (int)(i / 6272);            // 49*128
        int r = (int)(i - (long long)b * 6272);
        int l = r >> 7, c4 = r & 127;
        float4 xv = x4[i];
        float4 cv = ((const float4*)(ca + (size_t)b * 512))[c4];
        float g = sp[(size_t)b * 64 + l];
        float4 ov;
        ov.x = xv.x * cv.x * g;
        ov.y = xv.y * cv.y * g;
        ov.z = xv.z * cv.z * g;
        ov.w = xv.w * cv.w * g;
        o4[i] = ov;
    }
}

extern "C" void kernel_launch(void* const* d_in, const int* in_sizes, int n_in,
                              void* d_out, int out_size, void* d_ws, size_t ws_size,
                              hipStream_t stream) {
    (void)in_sizes; (void)n_in; (void)out_size;
    const float* x    = (const float*)d_in[0];
    const float* g_w  = (const float*)d_in[1];
    const float* l_w  = (const float*)d_in[2];
    const float* w3   = (const float*)d_in[3];
    const float* b3   = (const float*)d_in[4];
    const float* w5   = (const float*)d_in[5];
    const float* b5   = (const float*)d_in[6];
    const float* cw   = (const float*)d_in[7];
    const float* cb   = (const float*)d_in[8];
    const float* sw   = (const float*)d_in[9];
    const float* sb   = (const float*)d_in[10];
    const float* ssc  = (const float*)d_in[11];
    const float* sbi  = (const float*)d_in[12];
    float* outp = (float*)d_out;
    unsigned short* ws = (unsigned short*)d_ws;

    const size_t needed = (size_t)WS_WBYTES + (size_t)B_ * 512 * 4 + (size_t)B_ * 64 * 4;

    cvt_weights<<<dim3(512), dim3(256), 0, stream>>>(l_w, w3, w5, g_w, cw, ws);

    if (ws_size >= needed) {
        float* ca_out = (float*)((char*)d_ws + WS_WBYTES);
        float* sp_out = ca_out + (size_t)B_ * 512;
        mafn_gates<<<dim3(B_), dim3(512), 0, stream>>>(
            x, b3, b5, cb, sw, sb, ssc, sbi, ws, ca_out, sp_out);
        apply_gates<<<dim3(2048), dim3(256), 0, stream>>>(x, ca_out, sp_out, outp);
    } else {
        mafn_fused<<<dim3(B_), dim3(512), 0, stream>>>(
            x, b3, b5, cb, sw, sb, ssc, sbi, ws, outp);
    }
}

// Round 14
// 656.236 us; speedup vs baseline: 2.0534x; 2.0534x over previous
//
#include <hip/hip_runtime.h>
#include <math.h>

#define B_ 8192
#define L_ 49
#define C_ 512
#define R_ 128

typedef short   bf16x8 __attribute__((ext_vector_type(8)));
typedef unsigned short u16x8 __attribute__((ext_vector_type(8)));
typedef float   f32x4  __attribute__((ext_vector_type(4)));

// ws layout (ushort elements) — ALL weights wave-fragment-contiguous
#define WS_LWF   0           // 65536  [nt=8][ks=16][lane=64][8]
#define WS_WB3F  65536       // 36864  [tap=9][f=4][ks=2][lane=64][8]
#define WS_WB5F  102400      // 102400 [tap=25][f=4][ks=2][lane=64][8]
#define WS_GWF   204800      // 65536  like lwf
#define WS_CWF   270336      // 65536  [r8=16][c=512][8]

// shared memory layout (bytes), total 44304
#define SM_XB    0           // ush[49][256] swizzled, 25088
#define SM_XLB   25088       // ush[50][128] swizzled, 12800 | overlay P1/P2: maxb+sumf
#define SM_MAXB  25088       //   bf16 maxb[8][256] = 4096
#define SM_SUMF  29184       //   f32 sumf[8][256]  = 8192
#define SM_GA    37888       // bf16 ga[2][256] = 1024
#define SM_G     38912       // f32 g[2][128] = 1024
#define SM_CA    39936       // f32 ca[512] = 2048
#define SM_SPW   41984       // f32 spw[8][64] = 2048
#define SM_SP    44032       // f32[64]
#define SM_GDOT  44288       // f32[4]
#define SM_TOT   44304

__device__ __forceinline__ float bf2f(unsigned short u) {
    union { float f; unsigned int i; } v; v.i = ((unsigned int)u) << 16; return v.f;
}
__device__ __forceinline__ unsigned short f2bf(float f) {
    union { float f; unsigned int i; } v; v.f = f;
    unsigned int r = v.i + 0x7fffu + ((v.i >> 16) & 1u);
    return (unsigned short)(r >> 16);
}
__device__ __forceinline__ float star_relu(float x, float sc, float bi) {
    float r = fmaxf(x, 0.f);
    return sc * r * r + bi;
}
__device__ __forceinline__ float sigmoidf_(float x) {
    return 1.f / (1.f + __expf(-x));
}

// ---------------- pre-pass: convert + repack weights to fragment-contiguous bf16 ----------------
__global__ void cvt_weights(const float* __restrict__ lw, const float* __restrict__ w3,
                            const float* __restrict__ w5, const float* __restrict__ gw,
                            const float* __restrict__ cw, unsigned short* __restrict__ ws)
{
    int t = blockIdx.x * blockDim.x + threadIdx.x;
    int stride = gridDim.x * blockDim.x;
    for (int i = t; i < 65536; i += stride) {
        int j = i & 7, lane = (i >> 3) & 63, ks = (i >> 9) & 15, nt = i >> 13;
        int n = nt * 16 + (lane & 15);
        int k = ks * 32 + (lane >> 4) * 8 + j;
        ws[WS_LWF + i] = f2bf(lw[n * 512 + k]);
        ws[WS_GWF + i] = f2bf(gw[n * 512 + k]);
    }
    for (int i = t; i < 65536; i += stride) {
        int j = i & 7, c = (i >> 3) & 511, r8 = i >> 12;
        ws[WS_CWF + i] = f2bf(cw[c * 128 + r8 * 8 + j]);
    }
    for (int i = t; i < 36864; i += stride) {
        int j = i & 7, lane = (i >> 3) & 63, ks = (i >> 9) & 1, f = (i >> 10) & 3, tap = i >> 12;
        int oc = f * 16 + (lane & 15);
        int ic = ks * 32 + (lane >> 4) * 8 + j;
        ws[WS_WB3F + i] = f2bf(w3[(oc * 64 + ic) * 9 + tap]);
    }
    for (int i = t; i < 102400; i += stride) {
        int j = i & 7, lane = (i >> 3) & 63, ks = (i >> 9) & 1, f = (i >> 10) & 3, tap = i >> 12;
        int oc = f * 16 + (lane & 15);
        int ic = ks * 32 + (lane >> 4) * 8 + j;
        ws[WS_WB5F + i] = f2bf(w5[(oc * 64 + ic) * 25 + tap]);
    }
}

// ---------------- conv tap-GEMM with 1-tap-ahead B-fragment prefetch ----------------
template <int NTAP, int KD, int PAD, int COLBASE>
__device__ __forceinline__ void conv_mfma(const unsigned short* __restrict__ s_xlb,
                                          const unsigned short* __restrict__ wtbf,
                                          int m16, int kg, int ln, int f, f32x4 C[4])
{
    int lp_[4], i_[4], j_[4];
    #pragma unroll
    for (int mf = 0; mf < 4; ++mf) {
        lp_[mf] = mf * 16 + m16;
        i_[mf] = lp_[mf] / 7;
        j_[mf] = lp_[mf] % 7;
    }
    // prefetch tap 0's two B fragments
    bf16x8 cur0 = *(const bf16x8*)(wtbf + ((0 * 4 + f) * 2 + 0) * 512 + ln * 8);
    bf16x8 cur1 = *(const bf16x8*)(wtbf + ((0 * 4 + f) * 2 + 1) * 512 + ln * 8);
    #pragma unroll
    for (int tap = 0; tap < NTAP; ++tap) {
        bf16x8 nxt0 = cur0, nxt1 = cur1;
        if (tap + 1 < NTAP) {
            nxt0 = *(const bf16x8*)(wtbf + (((tap + 1) * 4 + f) * 2 + 0) * 512 + ln * 8);
            nxt1 = *(const bf16x8*)(wtbf + (((tap + 1) * 4 + f) * 2 + 1) * 512 + ln * 8);
        }
        const int dy = tap / KD - PAD, dx = tap % KD - PAD;
        int lc[4];
        #pragma unroll
        for (int mf = 0; mf < 4; ++mf) {
            int ii = i_[mf] + dy, jj = j_[mf] + dx;
            bool v = (lp_[mf] < 49) & (ii >= 0) & (ii < 7) & (jj >= 0) & (jj < 7);
            lc[mf] = v ? (ii * 7 + jj) : 49;              // row 49 is all zeros
        }
        #pragma unroll
        for (int mf = 0; mf < 4; ++mf) {
            int chunk0 = ((COLBASE >> 3) + kg) ^ (lc[mf] & 7);
            bf16x8 a = *(const bf16x8*)&s_xlb[lc[mf] * 128 + chunk0 * 8];
            C[mf] = __builtin_amdgcn_mfma_f32_16x16x32_bf16(a, cur0, C[mf], 0, 0, 0);
        }
        #pragma unroll
        for (int mf = 0; mf < 4; ++mf) {
            int chunk1 = ((COLBASE >> 3) + 4 + kg) ^ (lc[mf] & 7);
            bf16x8 a = *(const bf16x8*)&s_xlb[lc[mf] * 128 + chunk1 * 8];
            C[mf] = __builtin_amdgcn_mfma_f32_16x16x32_bf16(a, cur1, C[mf], 0, 0, 0);
        }
        cur0 = nxt0; cur1 = nxt1;
    }
}

// ---------------- main fused kernel: one block per batch ----------------
__global__ __launch_bounds__(512, 4)
void mafn_fused(const float* __restrict__ x,
                const float* __restrict__ b3, const float* __restrict__ b5,
                const float* __restrict__ cb, const float* __restrict__ sw,
                const float* __restrict__ sb, const float* __restrict__ ssc,
                const float* __restrict__ sbi,
                const unsigned short* __restrict__ ws,
                float* __restrict__ out)
{
    __shared__ __align__(16) unsigned char smem[SM_TOT];
    unsigned short* s_xb   = (unsigned short*)(smem + SM_XB);
    unsigned short* s_xlb  = (unsigned short*)(smem + SM_XLB);
    unsigned short* s_maxb = (unsigned short*)(smem + SM_MAXB);
    float*          s_sumf = (float*)(smem + SM_SUMF);
    unsigned short* s_ga   = (unsigned short*)(smem + SM_GA);
    float*          s_g    = (float*)(smem + SM_G);
    float*          s_ca   = (float*)(smem + SM_CA);
    float*          s_spw  = (float*)(smem + SM_SPW);
    float*          s_sp   = (float*)(smem + SM_SP);
    float*          s_gdot = (float*)(smem + SM_GDOT);

    const int b = blockIdx.x, t = threadIdx.x;
    const int wv = t >> 6, ln = t & 63;
    const int m16 = ln & 15, kg = ln >> 4;
    const float scale = ssc[0], sbias = sbi[0];

    const unsigned short* lwf  = ws + WS_LWF;
    const unsigned short* wb3f = ws + WS_WB3F;
    const unsigned short* wb5f = ws + WS_WB5F;
    const unsigned short* gwf  = ws + WS_GWF;
    const unsigned short* cwf  = ws + WS_CWF;

    f32x4 accA[4];       // x_l accumulators: this wave's n-fragment (n = wv*16+m16)
    f32x4 accG;          // g accumulator: this wave's n-fragment
    {
        const f32x4 z = {0.f, 0.f, 0.f, 0.f};
        #pragma unroll
        for (int mf = 0; mf < 4; ++mf) accA[mf] = z;
        accG = z;
    }

    const int l0 = wv * 6;
    const int nl = (wv < 7) ? 6 : 7;      // rows 42..48 for wave 7

    // ================= K-split halves: P1 load / P2 reduce / P3 GEMMs =================
    #pragma unroll 1
    for (int h = 0; h < 2; ++h) {
        // ---- P1: load x half (f32), partials, bf16 -> swizzled LDS ----
        {
            const float4* x4 = (const float4*)(x + (size_t)b * (L_ * C_)) + h * 64;
            float4 mx = {-3.4e38f, -3.4e38f, -3.4e38f, -3.4e38f};
            float4 sm = {0.f, 0.f, 0.f, 0.f};
            for (int li = 0; li < nl; ++li) {
                int l = l0 + li;
                float4 v = x4[l * 128 + ln];
                mx.x = fmaxf(mx.x, v.x); mx.y = fmaxf(mx.y, v.y);
                mx.z = fmaxf(mx.z, v.z); mx.w = fmaxf(mx.w, v.w);
                sm.x += v.x; sm.y += v.y; sm.z += v.z; sm.w += v.w;
                ushort4 p;
                p.x = f2bf(v.x); p.y = f2bf(v.y); p.z = f2bf(v.z); p.w = f2bf(v.w);
                int chunk = (ln >> 1) ^ (l & 7);
                *(ushort4*)&s_xb[l * 256 + chunk * 8 + (ln & 1) * 4] = p;
            }
            ushort4 pm;
            pm.x = f2bf(mx.x); pm.y = f2bf(mx.y); pm.z = f2bf(mx.z); pm.w = f2bf(mx.w);
            *(ushort4*)&s_maxb[wv * 256 + ln * 4] = pm;
            *(float4*)&s_sumf[wv * 256 + ln * 4] = sm;
        }
        __syncthreads();

        // ---- P2: finalize max/avg for this half -> bf16 A rows ----
        {
            if (t < 256) {
                int c = t;
                float m = bf2f(s_maxb[c]);
                #pragma unroll
                for (int i = 1; i < 8; ++i) m = fmaxf(m, bf2f(s_maxb[i * 256 + c]));
                s_ga[c] = f2bf(m);                       // exact: m already a bf16 value
            } else {
                int c = t - 256;
                float s = 0.f;
                #pragma unroll
                for (int i = 0; i < 8; ++i) s += s_sumf[i * 256 + c];
                s_ga[256 + c] = f2bf(s * (1.f / 49.f));
            }
        }
        __syncthreads();

        // ---- P3: x_l MFMA with all-8 B-frag register preload, then g MFMA ----
        {
            int rowA[4];
            #pragma unroll
            for (int mf = 0; mf < 4; ++mf) rowA[mf] = min(mf * 16 + m16, 48);

            bf16x8 bbuf[8];
            #pragma unroll
            for (int ks = 0; ks < 8; ++ks)
                bbuf[ks] = *(const bf16x8*)(lwf + (wv * 16 + h * 8 + ks) * 512 + ln * 8);
            #pragma unroll
            for (int ks = 0; ks < 8; ++ks) {
                #pragma unroll
                for (int mf = 0; mf < 4; ++mf) {
                    int chunk = (ks * 4 + kg) ^ (rowA[mf] & 7);
                    bf16x8 a = *(const bf16x8*)&s_xb[rowA[mf] * 256 + chunk * 8];
                    accA[mf] = __builtin_amdgcn_mfma_f32_16x16x32_bf16(a, bbuf[ks], accA[mf], 0, 0, 0);
                }
            }

            bf16x8 gbuf[8];
            #pragma unroll
            for (int ks = 0; ks < 8; ++ks)
                gbuf[ks] = *(const bf16x8*)(gwf + (wv * 16 + h * 8 + ks) * 512 + ln * 8);
            const bf16x8 zz = {0,0,0,0,0,0,0,0};
            #pragma unroll
            for (int ks = 0; ks < 8; ++ks) {
                bf16x8 a = (m16 < 2) ? *(const bf16x8*)&s_ga[m16 * 256 + ks * 32 + kg * 8] : zz;
                accG = __builtin_amdgcn_mfma_f32_16x16x32_bf16(a, gbuf[ks], accG, 0, 0, 0);
            }
        }
        __syncthreads();
    }

    // ---- P4: store x_l bf16 (swizzled, all waves) + g (kg==0 lanes) ----
    {
        if (t < 64) ((unsigned int*)(s_xlb + 49 * 128))[t] = 0;   // zero row 49
        const int n = wv * 16 + m16;
        #pragma unroll
        for (int mf = 0; mf < 4; ++mf) {
            #pragma unroll
            for (int rg = 0; rg < 4; ++rg) {
                int lp = mf * 16 + kg * 4 + rg;
                if (lp < 49) {
                    int idx = lp * 128 + ((((n >> 3) ^ (lp & 7)) << 3) + (n & 7));
                    s_xlb[idx] = f2bf(accA[mf][rg]);
                }
            }
        }
        if (kg == 0) {
            s_g[n]       = star_relu(accG[0], scale, sbias);   // row 0 = max -> g1
            s_g[128 + n] = star_relu(accG[1], scale, sbias);   // row 1 = avg -> g2
        }
    }
    __syncthreads();

    // ---- P5: waves 0-3: conv5 full  ||  waves 4-7: conv3 full + c_aggr + gdot ----
    const int f_ = wv & 3;
    const int oc_ = f_ * 16 + m16;
    {
        f32x4 C[4];
        const f32x4 z = {0.f, 0.f, 0.f, 0.f};
        #pragma unroll
        for (int mf = 0; mf < 4; ++mf) C[mf] = z;

        if (wv < 4) {
            conv_mfma<25, 5, 2, 64>(s_xlb, wb5f, m16, kg, ln, f_, C);   // 200 MFMA
        } else {
            conv_mfma< 9, 3, 1,  0>(s_xlb, wb3f, m16, kg, ln, f_, C);   // 72 MFMA
            // c_aggr: waves 4-7 = 256 threads, 2 channels each; cwf[r8][c][8] coalesced
            const int idx = t - 256;
            #pragma unroll
            for (int half = 0; half < 2; ++half) {
                int c = idx + half * 256;
                float a0 = 0.f, a1 = 0.f;
                #pragma unroll 4
                for (int r8 = 0; r8 < 16; ++r8) {
                    u16x8 w = *(const u16x8*)(cwf + r8 * 4096 + c * 8);
                    float p = 0.f;
                    #pragma unroll
                    for (int k = 0; k < 8; ++k)
                        p += bf2f(w[k]) * (s_g[r8 * 8 + k] + s_g[128 + r8 * 8 + k]);
                    if (r8 & 1) a1 += p; else a0 += p;
                }
                s_ca[c] = sigmoidf_(a0 + a1 + 2.f * cb[c]);
            }
            if (wv == 7) {
                float p = s_g[ln] * sw[128 + ln] + s_g[128 + ln] * sw[256 + ln]
                        + s_g[ln + 64] * sw[128 + ln + 64] + s_g[128 + ln + 64] * sw[256 + ln + 64];
                #pragma unroll
                for (int off = 32; off > 0; off >>= 1) p += __shfl_xor(p, off);
                if (ln == 0) s_gdot[0] = p;
            }
        }

        // epilogue: star_relu + sw-dot, reduce over this wave's 16 channels
        const bool is5 = (wv < 4);
        const int ch = is5 ? 64 + oc_ : oc_;
        const float bias = is5 ? b5[oc_] : b3[oc_];
        const float sww = sw[ch];
        #pragma unroll
        for (int mf = 0; mf < 4; ++mf) {
            #pragma unroll
            for (int rg = 0; rg < 4; ++rg) {
                int lp = mf * 16 + kg * 4 + rg;
                float v = (lp < 49) ? star_relu(C[mf][rg] + bias, scale, sbias) * sww : 0.f;
                v += __shfl_xor(v, 1);
                v += __shfl_xor(v, 2);
                v += __shfl_xor(v, 4);
                v += __shfl_xor(v, 8);
                if (m16 == 0 && lp < 49) s_spw[wv * 64 + lp] = v;
            }
        }
    }
    __syncthreads();

    // ---- P6: spatial gate (sum 8 wave partials) ----
    if (t < 49) {
        float s = s_gdot[0] + sb[0];
        #pragma unroll
        for (int w = 0; w < 8; ++w) s += s_spw[w * 64 + t];
        s_sp[t] = sigmoidf_(s);
    }
    __syncthreads();

    // ---- P7: out = x * ca[c] * sp[l] (x re-read f32, L2-hot) ----
    {
        const float4* x4 = (const float4*)(x + (size_t)b * (L_ * C_));
        float4* o4 = (float4*)(out + (size_t)b * (L_ * C_));
        const float4* ca4 = (const float4*)s_ca;
        for (int i = t; i < 49 * 128; i += 512) {
            int l = i >> 7, c4 = i & 127;
            float4 xv = x4[i];
            float g = s_sp[l];
            float4 cv = ca4[c4];
            float4 ov;
            ov.x = xv.x * cv.x * g;
            ov.y = xv.y * cv.y * g;
            ov.z = xv.z * cv.z * g;
            ov.w = xv.w * cv.w * g;
            o4[i] = ov;
        }
    }
}

extern "C" void kernel_launch(void* const* d_in, const int* in_sizes, int n_in,
                              void* d_out, int out_size, void* d_ws, size_t ws_size,
                              hipStream_t stream) {
    (void)in_sizes; (void)n_in; (void)ws_size; (void)out_size;
    const float* x    = (const float*)d_in[0];
    const float* g_w  = (const float*)d_in[1];
    const float* l_w  = (const float*)d_in[2];
    const float* w3   = (const float*)d_in[3];
    const float* b3   = (const float*)d_in[4];
    const float* w5   = (const float*)d_in[5];
    const float* b5   = (const float*)d_in[6];
    const float* cw   = (const float*)d_in[7];
    const float* cb   = (const float*)d_in[8];
    const float* sw   = (const float*)d_in[9];
    const float* sb   = (const float*)d_in[10];
    const float* ssc  = (const float*)d_in[11];
    const float* sbi  = (const float*)d_in[12];
    float* outp = (float*)d_out;
    unsigned short* ws = (unsigned short*)d_ws;

    cvt_weights<<<dim3(512), dim3(256), 0, stream>>>(l_w, w3, w5, g_w, cw, ws);
    mafn_fused<<<dim3(B_), dim3(512), 0, stream>>>(
        x, b3, b5, cb, sw, sb, ssc, sbi, ws, outp);
}

// Round 15
// 648.229 us; speedup vs baseline: 2.0787x; 1.0124x over previous
//
#include <hip/hip_runtime.h>
#include <math.h>

#define B_ 8192
#define L_ 49
#define C_ 512
#define R_ 128

typedef short   bf16x8 __attribute__((ext_vector_type(8)));
typedef unsigned short u16x8 __attribute__((ext_vector_type(8)));
typedef float   f32x4  __attribute__((ext_vector_type(4)));

// ws layout (ushort elements) — ALL weights wave-fragment-contiguous
#define WS_LWF   0           // 65536  [nt=8][ks=16][lane=64][8]
#define WS_WB3F  65536       // 36864  [tap=9][f=4][ks=2][lane=64][8]
#define WS_WB5F  102400      // 102400 [tap=25][f=4][ks=2][lane=64][8]
#define WS_GWF   204800      // 65536  like lwf
#define WS_CWF   270336      // 65536  [r8=16][c=512][8]

// shared memory layout (bytes), total 44304
#define SM_XB    0           // ush[49][256] swizzled, 25088
#define SM_XLB   25088       // ush[50][128] swizzled, 12800 | overlay P1/P2: maxb+sumf
#define SM_MAXB  25088       //   bf16 maxb[8][256] = 4096
#define SM_SUMF  29184       //   f32 sumf[8][256]  = 8192
#define SM_GA    37888       // bf16 ga[2][256] = 1024
#define SM_G     38912       // f32 g[2][128] = 1024
#define SM_CA    39936       // f32 ca[512] = 2048
#define SM_SPW   41984       // f32 spw[8][64] = 2048
#define SM_SP    44032       // f32[64]
#define SM_GDOT  44288       // f32[4]
#define SM_TOT   44304

__device__ __forceinline__ float bf2f(unsigned short u) {
    union { float f; unsigned int i; } v; v.i = ((unsigned int)u) << 16; return v.f;
}
__device__ __forceinline__ unsigned short f2bf(float f) {
    union { float f; unsigned int i; } v; v.f = f;
    unsigned int r = v.i + 0x7fffu + ((v.i >> 16) & 1u);
    return (unsigned short)(r >> 16);
}
__device__ __forceinline__ float star_relu(float x, float sc, float bi) {
    float r = fmaxf(x, 0.f);
    return sc * r * r + bi;
}
__device__ __forceinline__ float sigmoidf_(float x) {
    return 1.f / (1.f + __expf(-x));
}

// ---------------- pre-pass: convert + repack weights to fragment-contiguous bf16 ----------------
__global__ void cvt_weights(const float* __restrict__ lw, const float* __restrict__ w3,
                            const float* __restrict__ w5, const float* __restrict__ gw,
                            const float* __restrict__ cw, unsigned short* __restrict__ ws)
{
    int t = blockIdx.x * blockDim.x + threadIdx.x;
    int stride = gridDim.x * blockDim.x;
    for (int i = t; i < 65536; i += stride) {
        int j = i & 7, lane = (i >> 3) & 63, ks = (i >> 9) & 15, nt = i >> 13;
        int n = nt * 16 + (lane & 15);
        int k = ks * 32 + (lane >> 4) * 8 + j;
        ws[WS_LWF + i] = f2bf(lw[n * 512 + k]);
        ws[WS_GWF + i] = f2bf(gw[n * 512 + k]);
    }
    for (int i = t; i < 65536; i += stride) {
        int j = i & 7, c = (i >> 3) & 511, r8 = i >> 12;
        ws[WS_CWF + i] = f2bf(cw[c * 128 + r8 * 8 + j]);
    }
    for (int i = t; i < 36864; i += stride) {
        int j = i & 7, lane = (i >> 3) & 63, ks = (i >> 9) & 1, f = (i >> 10) & 3, tap = i >> 12;
        int oc = f * 16 + (lane & 15);
        int ic = ks * 32 + (lane >> 4) * 8 + j;
        ws[WS_WB3F + i] = f2bf(w3[(oc * 64 + ic) * 9 + tap]);
    }
    for (int i = t; i < 102400; i += stride) {
        int j = i & 7, lane = (i >> 3) & 63, ks = (i >> 9) & 1, f = (i >> 10) & 3, tap = i >> 12;
        int oc = f * 16 + (lane & 15);
        int ic = ks * 32 + (lane >> 4) * 8 + j;
        ws[WS_WB5F + i] = f2bf(w5[(oc * 64 + ic) * 25 + tap]);
    }
}

// ---------------- conv tap-GEMM with 1-tap-ahead B-fragment prefetch ----------------
template <int NTAP, int KD, int PAD, int COLBASE>
__device__ __forceinline__ void conv_mfma(const unsigned short* __restrict__ s_xlb,
                                          const unsigned short* __restrict__ wtbf,
                                          int m16, int kg, int ln, int f, f32x4 C[4])
{
    int lp_[4], i_[4], j_[4];
    #pragma unroll
    for (int mf = 0; mf < 4; ++mf) {
        lp_[mf] = mf * 16 + m16;
        i_[mf] = lp_[mf] / 7;
        j_[mf] = lp_[mf] % 7;
    }
    // prefetch tap 0's two B fragments
    bf16x8 cur0 = *(const bf16x8*)(wtbf + ((0 * 4 + f) * 2 + 0) * 512 + ln * 8);
    bf16x8 cur1 = *(const bf16x8*)(wtbf + ((0 * 4 + f) * 2 + 1) * 512 + ln * 8);
    #pragma unroll
    for (int tap = 0; tap < NTAP; ++tap) {
        bf16x8 nxt0 = cur0, nxt1 = cur1;
        if (tap + 1 < NTAP) {
            nxt0 = *(const bf16x8*)(wtbf + (((tap + 1) * 4 + f) * 2 + 0) * 512 + ln * 8);
            nxt1 = *(const bf16x8*)(wtbf + (((tap + 1) * 4 + f) * 2 + 1) * 512 + ln * 8);
        }
        const int dy = tap / KD - PAD, dx = tap % KD - PAD;
        int lc[4];
        #pragma unroll
        for (int mf = 0; mf < 4; ++mf) {
            int ii = i_[mf] + dy, jj = j_[mf] + dx;
            bool v = (lp_[mf] < 49) & (ii >= 0) & (ii < 7) & (jj >= 0) & (jj < 7);
            lc[mf] = v ? (ii * 7 + jj) : 49;              // row 49 is all zeros
        }
        #pragma unroll
        for (int mf = 0; mf < 4; ++mf) {
            int chunk0 = ((COLBASE >> 3) + kg) ^ (lc[mf] & 7);
            bf16x8 a = *(const bf16x8*)&s_xlb[lc[mf] * 128 + chunk0 * 8];
            C[mf] = __builtin_amdgcn_mfma_f32_16x16x32_bf16(a, cur0, C[mf], 0, 0, 0);
        }
        #pragma unroll
        for (int mf = 0; mf < 4; ++mf) {
            int chunk1 = ((COLBASE >> 3) + 4 + kg) ^ (lc[mf] & 7);
            bf16x8 a = *(const bf16x8*)&s_xlb[lc[mf] * 128 + chunk1 * 8];
            C[mf] = __builtin_amdgcn_mfma_f32_16x16x32_bf16(a, cur1, C[mf], 0, 0, 0);
        }
        cur0 = nxt0; cur1 = nxt1;
    }
}

// ---------------- main fused kernel: one block per batch ----------------
__global__ __launch_bounds__(512, 4)
void mafn_fused(const float* __restrict__ x,
                const float* __restrict__ b3, const float* __restrict__ b5,
                const float* __restrict__ cb, const float* __restrict__ sw,
                const float* __restrict__ sb, const float* __restrict__ ssc,
                const float* __restrict__ sbi,
                const unsigned short* __restrict__ ws,
                float* __restrict__ out)
{
    __shared__ __align__(16) unsigned char smem[SM_TOT];
    unsigned short* s_xb   = (unsigned short*)(smem + SM_XB);
    unsigned short* s_xlb  = (unsigned short*)(smem + SM_XLB);
    unsigned short* s_maxb = (unsigned short*)(smem + SM_MAXB);
    float*          s_sumf = (float*)(smem + SM_SUMF);
    unsigned short* s_ga   = (unsigned short*)(smem + SM_GA);
    float*          s_g    = (float*)(smem + SM_G);
    float*          s_ca   = (float*)(smem + SM_CA);
    float*          s_spw  = (float*)(smem + SM_SPW);
    float*          s_sp   = (float*)(smem + SM_SP);
    float*          s_gdot = (float*)(smem + SM_GDOT);

    const int b = blockIdx.x, t = threadIdx.x;
    const int wv = t >> 6, ln = t & 63;
    const int m16 = ln & 15, kg = ln >> 4;
    const float scale = ssc[0], sbias = sbi[0];

    const unsigned short* lwf  = ws + WS_LWF;
    const unsigned short* wb3f = ws + WS_WB3F;
    const unsigned short* wb5f = ws + WS_WB5F;
    const unsigned short* gwf  = ws + WS_GWF;
    const unsigned short* cwf  = ws + WS_CWF;

    f32x4 accA[4];       // x_l accumulators: this wave's n-fragment (n = wv*16+m16)
    f32x4 accG;          // g accumulator: this wave's n-fragment
    {
        const f32x4 z = {0.f, 0.f, 0.f, 0.f};
        #pragma unroll
        for (int mf = 0; mf < 4; ++mf) accA[mf] = z;
        accG = z;
    }

    const int l0 = wv * 6;
    const int nl = (wv < 7) ? 6 : 7;      // rows 42..48 for wave 7

    // ================= K-split halves: P1 load / P2 reduce / P3 GEMMs =================
    #pragma unroll 1
    for (int h = 0; h < 2; ++h) {
        // ---- P1: load x half (f32), partials, bf16 -> swizzled LDS ----
        {
            const float4* x4 = (const float4*)(x + (size_t)b * (L_ * C_)) + h * 64;
            float4 mx = {-3.4e38f, -3.4e38f, -3.4e38f, -3.4e38f};
            float4 sm = {0.f, 0.f, 0.f, 0.f};
            for (int li = 0; li < nl; ++li) {
                int l = l0 + li;
                float4 v = x4[l * 128 + ln];
                mx.x = fmaxf(mx.x, v.x); mx.y = fmaxf(mx.y, v.y);
                mx.z = fmaxf(mx.z, v.z); mx.w = fmaxf(mx.w, v.w);
                sm.x += v.x; sm.y += v.y; sm.z += v.z; sm.w += v.w;
                ushort4 p;
                p.x = f2bf(v.x); p.y = f2bf(v.y); p.z = f2bf(v.z); p.w = f2bf(v.w);
                int chunk = (ln >> 1) ^ (l & 7);
                *(ushort4*)&s_xb[l * 256 + chunk * 8 + (ln & 1) * 4] = p;
            }
            ushort4 pm;
            pm.x = f2bf(mx.x); pm.y = f2bf(mx.y); pm.z = f2bf(mx.z); pm.w = f2bf(mx.w);
            *(ushort4*)&s_maxb[wv * 256 + ln * 4] = pm;
            *(float4*)&s_sumf[wv * 256 + ln * 4] = sm;
        }
        __syncthreads();

        // ---- P2: finalize max/avg for this half -> bf16 A rows ----
        {
            if (t < 256) {
                int c = t;
                float m = bf2f(s_maxb[c]);
                #pragma unroll
                for (int i = 1; i < 8; ++i) m = fmaxf(m, bf2f(s_maxb[i * 256 + c]));
                s_ga[c] = f2bf(m);                       // exact: m already a bf16 value
            } else {
                int c = t - 256;
                float s = 0.f;
                #pragma unroll
                for (int i = 0; i < 8; ++i) s += s_sumf[i * 256 + c];
                s_ga[256 + c] = f2bf(s * (1.f / 49.f));
            }
        }
        __syncthreads();

        // ---- P3: x_l MFMA with 2-ahead rolling B prefetch, then g MFMA ----
        {
            int rowA[4];
            #pragma unroll
            for (int mf = 0; mf < 4; ++mf) rowA[mf] = min(mf * 16 + m16, 48);

            bf16x8 bb0 = *(const bf16x8*)(lwf + (wv * 16 + h * 8 + 0) * 512 + ln * 8);
            bf16x8 bb1 = *(const bf16x8*)(lwf + (wv * 16 + h * 8 + 1) * 512 + ln * 8);
            #pragma unroll
            for (int ks = 0; ks < 8; ++ks) {
                bf16x8 bn = bb1;
                if (ks + 2 < 8)
                    bn = *(const bf16x8*)(lwf + (wv * 16 + h * 8 + ks + 2) * 512 + ln * 8);
                #pragma unroll
                for (int mf = 0; mf < 4; ++mf) {
                    int chunk = (ks * 4 + kg) ^ (rowA[mf] & 7);
                    bf16x8 a = *(const bf16x8*)&s_xb[rowA[mf] * 256 + chunk * 8];
                    accA[mf] = __builtin_amdgcn_mfma_f32_16x16x32_bf16(a, bb0, accA[mf], 0, 0, 0);
                }
                bb0 = bb1; bb1 = bn;
            }

            bf16x8 gb0 = *(const bf16x8*)(gwf + (wv * 16 + h * 8 + 0) * 512 + ln * 8);
            bf16x8 gb1 = *(const bf16x8*)(gwf + (wv * 16 + h * 8 + 1) * 512 + ln * 8);
            const bf16x8 zz = {0,0,0,0,0,0,0,0};
            #pragma unroll
            for (int ks = 0; ks < 8; ++ks) {
                bf16x8 gn = gb1;
                if (ks + 2 < 8)
                    gn = *(const bf16x8*)(gwf + (wv * 16 + h * 8 + ks + 2) * 512 + ln * 8);
                bf16x8 a = (m16 < 2) ? *(const bf16x8*)&s_ga[m16 * 256 + ks * 32 + kg * 8] : zz;
                accG = __builtin_amdgcn_mfma_f32_16x16x32_bf16(a, gb0, accG, 0, 0, 0);
                gb0 = gb1; gb1 = gn;
            }
        }
        __syncthreads();
    }

    // ---- P4: store x_l bf16 (swizzled, all waves) + g (kg==0 lanes) ----
    {
        if (t < 64) ((unsigned int*)(s_xlb + 49 * 128))[t] = 0;   // zero row 49
        const int n = wv * 16 + m16;
        #pragma unroll
        for (int mf = 0; mf < 4; ++mf) {
            #pragma unroll
            for (int rg = 0; rg < 4; ++rg) {
                int lp = mf * 16 + kg * 4 + rg;
                if (lp < 49) {
                    int idx = lp * 128 + ((((n >> 3) ^ (lp & 7)) << 3) + (n & 7));
                    s_xlb[idx] = f2bf(accA[mf][rg]);
                }
            }
        }
        if (kg == 0) {
            s_g[n]       = star_relu(accG[0], scale, sbias);   // row 0 = max -> g1
            s_g[128 + n] = star_relu(accG[1], scale, sbias);   // row 1 = avg -> g2
        }
    }
    __syncthreads();

    // ---- P5: waves 0-3: conv5 full  ||  waves 4-7: conv3 full + c_aggr + gdot ----
    const int f_ = wv & 3;
    const int oc_ = f_ * 16 + m16;
    {
        f32x4 C[4];
        const f32x4 z = {0.f, 0.f, 0.f, 0.f};
        #pragma unroll
        for (int mf = 0; mf < 4; ++mf) C[mf] = z;

        if (wv < 4) {
            conv_mfma<25, 5, 2, 64>(s_xlb, wb5f, m16, kg, ln, f_, C);   // 200 MFMA
        } else {
            conv_mfma< 9, 3, 1,  0>(s_xlb, wb3f, m16, kg, ln, f_, C);   // 72 MFMA
            // c_aggr: waves 4-7 = 256 threads, 2 channels each; cwf[r8][c][8] coalesced
            const int idx = t - 256;
            #pragma unroll
            for (int half = 0; half < 2; ++half) {
                int c = idx + half * 256;
                float a0 = 0.f, a1 = 0.f;
                #pragma unroll 4
                for (int r8 = 0; r8 < 16; ++r8) {
                    u16x8 w = *(const u16x8*)(cwf + r8 * 4096 + c * 8);
                    float p = 0.f;
                    #pragma unroll
                    for (int k = 0; k < 8; ++k)
                        p += bf2f(w[k]) * (s_g[r8 * 8 + k] + s_g[128 + r8 * 8 + k]);
                    if (r8 & 1) a1 += p; else a0 += p;
                }
                s_ca[c] = sigmoidf_(a0 + a1 + 2.f * cb[c]);
            }
            if (wv == 7) {
                float p = s_g[ln] * sw[128 + ln] + s_g[128 + ln] * sw[256 + ln]
                        + s_g[ln + 64] * sw[128 + ln + 64] + s_g[128 + ln + 64] * sw[256 + ln + 64];
                #pragma unroll
                for (int off = 32; off > 0; off >>= 1) p += __shfl_xor(p, off);
                if (ln == 0) s_gdot[0] = p;
            }
        }

        // epilogue: star_relu + sw-dot, reduce over this wave's 16 channels
        const bool is5 = (wv < 4);
        const int ch = is5 ? 64 + oc_ : oc_;
        const float bias = is5 ? b5[oc_] : b3[oc_];
        const float sww = sw[ch];
        #pragma unroll
        for (int mf = 0; mf < 4; ++mf) {
            #pragma unroll
            for (int rg = 0; rg < 4; ++rg) {
                int lp = mf * 16 + kg * 4 + rg;
                float v = (lp < 49) ? star_relu(C[mf][rg] + bias, scale, sbias) * sww : 0.f;
                v += __shfl_xor(v, 1);
                v += __shfl_xor(v, 2);
                v += __shfl_xor(v, 4);
                v += __shfl_xor(v, 8);
                if (m16 == 0 && lp < 49) s_spw[wv * 64 + lp] = v;
            }
        }
    }
    __syncthreads();

    // ---- P6: spatial gate (sum 8 wave partials) ----
    if (t < 49) {
        float s = s_gdot[0] + sb[0];
        #pragma unroll
        for (int w = 0; w < 8; ++w) s += s_spw[w * 64 + t];
        s_sp[t] = sigmoidf_(s);
    }
    __syncthreads();

    // ---- P7: out = x * ca[c] * sp[l] (x re-read f32, L2-hot) ----
    {
        const float4* x4 = (const float4*)(x + (size_t)b * (L_ * C_));
        float4* o4 = (float4*)(out + (size_t)b * (L_ * C_));
        const float4* ca4 = (const float4*)s_ca;
        for (int i = t; i < 49 * 128; i += 512) {
            int l = i >> 7, c4 = i & 127;
            float4 xv = x4[i];
            float g = s_sp[l];
            float4 cv = ca4[c4];
            float4 ov;
            ov.x = xv.x * cv.x * g;
            ov.y = xv.y * cv.y * g;
            ov.z = xv.z * cv.z * g;
            ov.w = xv.w * cv.w * g;
            o4[i] = ov;
        }
    }
}

extern "C" void kernel_launch(void* const* d_in, const int* in_sizes, int n_in,
                              void* d_out, int out_size, void* d_ws, size_t ws_size,
                              hipStream_t stream) {
    (void)in_sizes; (void)n_in; (void)ws_size; (void)out_size;
    const float* x    = (const float*)d_in[0];
    const float* g_w  = (const float*)d_in[1];
    const float* l_w  = (const float*)d_in[2];
    const float* w3   = (const float*)d_in[3];
    const float* b3   = (const float*)d_in[4];
    const float* w5   = (const float*)d_in[5];
    const float* b5   = (const float*)d_in[6];
    const float* cw   = (const float*)d_in[7];
    const float* cb   = (const float*)d_in[8];
    const float* sw   = (const float*)d_in[9];
    const float* sb   = (const float*)d_in[10];
    const float* ssc  = (const float*)d_in[11];
    const float* sbi  = (const float*)d_in[12];
    float* outp = (float*)d_out;
    unsigned short* ws = (unsigned short*)d_ws;

    cvt_weights<<<dim3(512), dim3(256), 0, stream>>>(l_w, w3, w5, g_w, cw, ws);
    mafn_fused<<<dim3(B_), dim3(512), 0, stream>>>(
        x, b3, b5, cb, sw, sb, ssc, sbi, ws, outp);
}

// Round 16
// 601.757 us; speedup vs baseline: 2.2392x; 1.0772x over previous
//
#include <hip/hip_runtime.h>
#include <math.h>

#define B_ 8192
#define L_ 49
#define C_ 512
#define R_ 128

typedef short   bf16x8 __attribute__((ext_vector_type(8)));
typedef unsigned short u16x8 __attribute__((ext_vector_type(8)));
typedef float   f32x4  __attribute__((ext_vector_type(4)));

// ws layout (ushort elements) — ALL weights wave-fragment-contiguous
#define WS_LWF   0           // 65536  [nt=8][ks=16][lane=64][8]
#define WS_WB3F  65536       // 36864  [tap=9][f=4][ks=2][lane=64][8]
#define WS_WB5F  102400      // 102400 [tap=25][f=4][ks=2][lane=64][8]
#define WS_GWF   204800      // 65536  like lwf
#define WS_CWF   270336      // 65536  [r8=16][c=512][8]

// shared memory layout (bytes), total 65024 -> 2 blocks/CU
// xb region [0, 50176): live P1-P3; overlaid by g/ca/spw/sp/gdot (written P4+)
#define SM_G     0           // f32[2][128] = 1024
#define SM_CA    1024        // f32[512] = 2048
#define SM_SPW   3072        // f32[8][64] = 2048
#define SM_SP    5120        // f32[64] = 256
#define SM_GDOT  5376        // f32[4] = 16
#define SM_XB    0           // ush[49][512] swizzled = 50176
// xlb region [50176, 62976): overlaid by maxb+sumf (live P1-P2 only)
#define SM_XLB   50176       // ush[50][128] swizzled = 12800
#define SM_MAXB  50176       //   bf16[4][512] = 4096
#define SM_SUMF  54272       //   f32[4][512]  = 8192
#define SM_GA    62976       // bf16[2][512] = 2048
#define SM_TOT   65024

__device__ __forceinline__ float bf2f(unsigned short u) {
    union { float f; unsigned int i; } v; v.i = ((unsigned int)u) << 16; return v.f;
}
__device__ __forceinline__ unsigned short f2bf(float f) {
    union { float f; unsigned int i; } v; v.f = f;
    unsigned int r = v.i + 0x7fffu + ((v.i >> 16) & 1u);
    return (unsigned short)(r >> 16);
}
__device__ __forceinline__ float star_relu(float x, float sc, float bi) {
    float r = fmaxf(x, 0.f);
    return sc * r * r + bi;
}
__device__ __forceinline__ float sigmoidf_(float x) {
    return 1.f / (1.f + __expf(-x));
}

// ---------------- pre-pass: convert + repack weights (unchanged layouts) ----------------
__global__ void cvt_weights(const float* __restrict__ lw, const float* __restrict__ w3,
                            const float* __restrict__ w5, const float* __restrict__ gw,
                            const float* __restrict__ cw, unsigned short* __restrict__ ws)
{
    int t = blockIdx.x * blockDim.x + threadIdx.x;
    int stride = gridDim.x * blockDim.x;
    for (int i = t; i < 65536; i += stride) {
        int j = i & 7, lane = (i >> 3) & 63, ks = (i >> 9) & 15, nt = i >> 13;
        int n = nt * 16 + (lane & 15);
        int k = ks * 32 + (lane >> 4) * 8 + j;
        ws[WS_LWF + i] = f2bf(lw[n * 512 + k]);
        ws[WS_GWF + i] = f2bf(gw[n * 512 + k]);
    }
    for (int i = t; i < 65536; i += stride) {
        int j = i & 7, c = (i >> 3) & 511, r8 = i >> 12;
        ws[WS_CWF + i] = f2bf(cw[c * 128 + r8 * 8 + j]);
    }
    for (int i = t; i < 36864; i += stride) {
        int j = i & 7, lane = (i >> 3) & 63, ks = (i >> 9) & 1, f = (i >> 10) & 3, tap = i >> 12;
        int oc = f * 16 + (lane & 15);
        int ic = ks * 32 + (lane >> 4) * 8 + j;
        ws[WS_WB3F + i] = f2bf(w3[(oc * 64 + ic) * 9 + tap]);
    }
    for (int i = t; i < 102400; i += stride) {
        int j = i & 7, lane = (i >> 3) & 63, ks = (i >> 9) & 1, f = (i >> 10) & 3, tap = i >> 12;
        int oc = f * 16 + (lane & 15);
        int ic = ks * 32 + (lane >> 4) * 8 + j;
        ws[WS_WB5F + i] = f2bf(w5[(oc * 64 + ic) * 25 + tap]);
    }
}

// ---------------- conv tap-GEMM with 1-tap-ahead B-fragment prefetch ----------------
template <int NTAP, int KD, int PAD, int COLBASE>
__device__ __forceinline__ void conv_mfma(const unsigned short* __restrict__ s_xlb,
                                          const unsigned short* __restrict__ wtbf,
                                          int m16, int kg, int ln, int f, f32x4 C[4])
{
    int lp_[4], i_[4], j_[4];
    #pragma unroll
    for (int mf = 0; mf < 4; ++mf) {
        lp_[mf] = mf * 16 + m16;
        i_[mf] = lp_[mf] / 7;
        j_[mf] = lp_[mf] % 7;
    }
    bf16x8 cur0 = *(const bf16x8*)(wtbf + ((0 * 4 + f) * 2 + 0) * 512 + ln * 8);
    bf16x8 cur1 = *(const bf16x8*)(wtbf + ((0 * 4 + f) * 2 + 1) * 512 + ln * 8);
    #pragma unroll
    for (int tap = 0; tap < NTAP; ++tap) {
        bf16x8 nxt0 = cur0, nxt1 = cur1;
        if (tap + 1 < NTAP) {
            nxt0 = *(const bf16x8*)(wtbf + (((tap + 1) * 4 + f) * 2 + 0) * 512 + ln * 8);
            nxt1 = *(const bf16x8*)(wtbf + (((tap + 1) * 4 + f) * 2 + 1) * 512 + ln * 8);
        }
        const int dy = tap / KD - PAD, dx = tap % KD - PAD;
        int lc[4];
        #pragma unroll
        for (int mf = 0; mf < 4; ++mf) {
            int ii = i_[mf] + dy, jj = j_[mf] + dx;
            bool v = (lp_[mf] < 49) & (ii >= 0) & (ii < 7) & (jj >= 0) & (jj < 7);
            lc[mf] = v ? (ii * 7 + jj) : 49;              // row 49 is all zeros
        }
        #pragma unroll
        for (int mf = 0; mf < 4; ++mf) {
            int chunk0 = ((COLBASE >> 3) + kg) ^ (lc[mf] & 7);
            bf16x8 a = *(const bf16x8*)&s_xlb[lc[mf] * 128 + chunk0 * 8];
            C[mf] = __builtin_amdgcn_mfma_f32_16x16x32_bf16(a, cur0, C[mf], 0, 0, 0);
        }
        #pragma unroll
        for (int mf = 0; mf < 4; ++mf) {
            int chunk1 = ((COLBASE >> 3) + 4 + kg) ^ (lc[mf] & 7);
            bf16x8 a = *(const bf16x8*)&s_xlb[lc[mf] * 128 + chunk1 * 8];
            C[mf] = __builtin_amdgcn_mfma_f32_16x16x32_bf16(a, cur1, C[mf], 0, 0, 0);
        }
        cur0 = nxt0; cur1 = nxt1;
    }
}

// ---------------- main fused kernel: one block per batch, single-pass K ----------------
__global__ __launch_bounds__(512, 4)
void mafn_fused(const float* __restrict__ x,
                const float* __restrict__ b3, const float* __restrict__ b5,
                const float* __restrict__ cb, const float* __restrict__ sw,
                const float* __restrict__ sb, const float* __restrict__ ssc,
                const float* __restrict__ sbi,
                const unsigned short* __restrict__ ws,
                float* __restrict__ out)
{
    __shared__ __align__(16) unsigned char smem[SM_TOT];
    unsigned short* s_xb   = (unsigned short*)(smem + SM_XB);
    unsigned short* s_xlb  = (unsigned short*)(smem + SM_XLB);
    unsigned short* s_maxb = (unsigned short*)(smem + SM_MAXB);
    float*          s_sumf = (float*)(smem + SM_SUMF);
    unsigned short* s_ga   = (unsigned short*)(smem + SM_GA);
    float*          s_g    = (float*)(smem + SM_G);
    float*          s_ca   = (float*)(smem + SM_CA);
    float*          s_spw  = (float*)(smem + SM_SPW);
    float*          s_sp   = (float*)(smem + SM_SP);
    float*          s_gdot = (float*)(smem + SM_GDOT);

    const int b = blockIdx.x, t = threadIdx.x;
    const int wv = t >> 6, ln = t & 63;
    const int m16 = ln & 15, kg = ln >> 4;
    const float scale = ssc[0], sbias = sbi[0];

    const unsigned short* lwf  = ws + WS_LWF;
    const unsigned short* wb3f = ws + WS_WB3F;
    const unsigned short* wb5f = ws + WS_WB5F;
    const unsigned short* gwf  = ws + WS_GWF;
    const unsigned short* cwf  = ws + WS_CWF;

    f32x4 accA[4];       // x_l accumulators: this wave's n-fragment (n = wv*16+m16)
    f32x4 accG;          // g accumulator
    {
        const f32x4 z = {0.f, 0.f, 0.f, 0.f};
        #pragma unroll
        for (int mf = 0; mf < 4; ++mf) accA[mf] = z;
        accG = z;
    }

    // ---- P1: load full x (f32), per-group partials, bf16 -> swizzled LDS ----
    {
        const float4* x4 = (const float4*)(x + (size_t)b * (L_ * C_));
        const int c4 = t & 127, rg = t >> 7;          // 4 groups x 128 threads, full rows
        const int l0 = rg * 12;
        const int nl = (rg < 3) ? 12 : 13;
        float4 mx = {-3.4e38f, -3.4e38f, -3.4e38f, -3.4e38f};
        float4 sm = {0.f, 0.f, 0.f, 0.f};
        for (int li = 0; li < nl; ++li) {
            int l = l0 + li;
            float4 v = x4[l * 128 + c4];
            mx.x = fmaxf(mx.x, v.x); mx.y = fmaxf(mx.y, v.y);
            mx.z = fmaxf(mx.z, v.z); mx.w = fmaxf(mx.w, v.w);
            sm.x += v.x; sm.y += v.y; sm.z += v.z; sm.w += v.w;
            ushort4 p;
            p.x = f2bf(v.x); p.y = f2bf(v.y); p.z = f2bf(v.z); p.w = f2bf(v.w);
            int chunk = (c4 >> 1) ^ (l & 7);          // 64 chunks/row, XOR low 3 bits
            *(ushort4*)&s_xb[l * 512 + chunk * 8 + (c4 & 1) * 4] = p;
        }
        ushort4 pm;
        pm.x = f2bf(mx.x); pm.y = f2bf(mx.y); pm.z = f2bf(mx.z); pm.w = f2bf(mx.w);
        *(ushort4*)&s_maxb[rg * 512 + c4 * 4] = pm;
        *(float4*)&s_sumf[rg * 512 + c4 * 4] = sm;
    }
    __syncthreads();

    // ---- P2: finalize max/avg -> bf16 A rows (all 512 threads, 1 channel each) ----
    {
        int c = t;
        float m = bf2f(s_maxb[c]);
        #pragma unroll
        for (int i = 1; i < 4; ++i) m = fmaxf(m, bf2f(s_maxb[i * 512 + c]));
        float s = 0.f;
        #pragma unroll
        for (int i = 0; i < 4; ++i) s += s_sumf[i * 512 + c];
        s_ga[c] = f2bf(m);                            // exact: m already a bf16 value
        s_ga[512 + c] = f2bf(s * (1.f / 49.f));
    }
    __syncthreads();

    // ---- P3: x_l MFMA (full K, 2-ahead rolling B prefetch), then g MFMA ----
    {
        int rowA[4];
        #pragma unroll
        for (int mf = 0; mf < 4; ++mf) rowA[mf] = min(mf * 16 + m16, 48);

        bf16x8 bb0 = *(const bf16x8*)(lwf + (wv * 16 + 0) * 512 + ln * 8);
        bf16x8 bb1 = *(const bf16x8*)(lwf + (wv * 16 + 1) * 512 + ln * 8);
        #pragma unroll
        for (int ks = 0; ks < 16; ++ks) {
            bf16x8 bn = bb1;
            if (ks + 2 < 16)
                bn = *(const bf16x8*)(lwf + (wv * 16 + ks + 2) * 512 + ln * 8);
            #pragma unroll
            for (int mf = 0; mf < 4; ++mf) {
                int chunk = (ks * 4 + kg) ^ (rowA[mf] & 7);
                bf16x8 a = *(const bf16x8*)&s_xb[rowA[mf] * 512 + chunk * 8];
                accA[mf] = __builtin_amdgcn_mfma_f32_16x16x32_bf16(a, bb0, accA[mf], 0, 0, 0);
            }
            bb0 = bb1; bb1 = bn;
        }

        bf16x8 gb0 = *(const bf16x8*)(gwf + (wv * 16 + 0) * 512 + ln * 8);
        bf16x8 gb1 = *(const bf16x8*)(gwf + (wv * 16 + 1) * 512 + ln * 8);
        const bf16x8 zz = {0,0,0,0,0,0,0,0};
        #pragma unroll
        for (int ks = 0; ks < 16; ++ks) {
            bf16x8 gn = gb1;
            if (ks + 2 < 16)
                gn = *(const bf16x8*)(gwf + (wv * 16 + ks + 2) * 512 + ln * 8);
            bf16x8 a = (m16 < 2) ? *(const bf16x8*)&s_ga[m16 * 512 + ks * 32 + kg * 8] : zz;
            accG = __builtin_amdgcn_mfma_f32_16x16x32_bf16(a, gb0, accG, 0, 0, 0);
            gb0 = gb1; gb1 = gn;
        }
    }
    __syncthreads();

    // ---- P4: store x_l bf16 (swizzled) + g (kg==0 lanes); xb region now dead ----
    {
        if (t < 64) ((unsigned int*)(s_xlb + 49 * 128))[t] = 0;   // zero row 49
        const int n = wv * 16 + m16;
        #pragma unroll
        for (int mf = 0; mf < 4; ++mf) {
            #pragma unroll
            for (int rg = 0; rg < 4; ++rg) {
                int lp = mf * 16 + kg * 4 + rg;
                if (lp < 49) {
                    int idx = lp * 128 + ((((n >> 3) ^ (lp & 7)) << 3) + (n & 7));
                    s_xlb[idx] = f2bf(accA[mf][rg]);
                }
            }
        }
        if (kg == 0) {
            s_g[n]       = star_relu(accG[0], scale, sbias);   // row 0 = max -> g1
            s_g[128 + n] = star_relu(accG[1], scale, sbias);   // row 1 = avg -> g2
        }
    }
    __syncthreads();

    // ---- P5: waves 0-3: conv5 full  ||  waves 4-7: conv3 full + c_aggr + gdot ----
    const int f_ = wv & 3;
    const int oc_ = f_ * 16 + m16;
    {
        f32x4 C[4];
        const f32x4 z = {0.f, 0.f, 0.f, 0.f};
        #pragma unroll
        for (int mf = 0; mf < 4; ++mf) C[mf] = z;

        if (wv < 4) {
            conv_mfma<25, 5, 2, 64>(s_xlb, wb5f, m16, kg, ln, f_, C);   // 200 MFMA
        } else {
            conv_mfma< 9, 3, 1,  0>(s_xlb, wb3f, m16, kg, ln, f_, C);   // 72 MFMA
            // c_aggr: waves 4-7 = 256 threads, 2 channels each; cwf[r8][c][8] coalesced
            const int idx = t - 256;
            #pragma unroll
            for (int half = 0; half < 2; ++half) {
                int c = idx + half * 256;
                float a0 = 0.f, a1 = 0.f;
                #pragma unroll 4
                for (int r8 = 0; r8 < 16; ++r8) {
                    u16x8 w = *(const u16x8*)(cwf + r8 * 4096 + c * 8);
                    float p = 0.f;
                    #pragma unroll
                    for (int k = 0; k < 8; ++k)
                        p += bf2f(w[k]) * (s_g[r8 * 8 + k] + s_g[128 + r8 * 8 + k]);
                    if (r8 & 1) a1 += p; else a0 += p;
                }
                s_ca[c] = sigmoidf_(a0 + a1 + 2.f * cb[c]);
            }
            if (wv == 7) {
                float p = s_g[ln] * sw[128 + ln] + s_g[128 + ln] * sw[256 + ln]
                        + s_g[ln + 64] * sw[128 + ln + 64] + s_g[128 + ln + 64] * sw[256 + ln + 64];
                #pragma unroll
                for (int off = 32; off > 0; off >>= 1) p += __shfl_xor(p, off);
                if (ln == 0) s_gdot[0] = p;
            }
        }

        // epilogue: star_relu + sw-dot, reduce over this wave's 16 channels
        const bool is5 = (wv < 4);
        const int ch = is5 ? 64 + oc_ : oc_;
        const float bias = is5 ? b5[oc_] : b3[oc_];
        const float sww = sw[ch];
        #pragma unroll
        for (int mf = 0; mf < 4; ++mf) {
            #pragma unroll
            for (int rg = 0; rg < 4; ++rg) {
                int lp = mf * 16 + kg * 4 + rg;
                float v = (lp < 49) ? star_relu(C[mf][rg] + bias, scale, sbias) * sww : 0.f;
                v += __shfl_xor(v, 1);
                v += __shfl_xor(v, 2);
                v += __shfl_xor(v, 4);
                v += __shfl_xor(v, 8);
                if (m16 == 0 && lp < 49) s_spw[wv * 64 + lp] = v;
            }
        }
    }
    __syncthreads();

    // ---- P6: spatial gate (sum 8 wave partials) ----
    if (t < 49) {
        float s = s_gdot[0] + sb[0];
        #pragma unroll
        for (int w = 0; w < 8; ++w) s += s_spw[w * 64 + t];
        s_sp[t] = sigmoidf_(s);
    }
    __syncthreads();

    // ---- P7: out = x * ca[c] * sp[l] (x re-read f32, L2-hot) ----
    {
        const float4* x4 = (const float4*)(x + (size_t)b * (L_ * C_));
        float4* o4 = (float4*)(out + (size_t)b * (L_ * C_));
        const int c4 = t & 127;
        const float4 cv = *(const float4*)&s_ca[c4 * 4];
        for (int i = t; i < 49 * 128; i += 512) {
            int l = i >> 7;
            float4 xv = x4[i];
            float g = s_sp[l];
            float4 ov;
            ov.x = xv.x * cv.x * g;
            ov.y = xv.y * cv.y * g;
            ov.z = xv.z * cv.z * g;
            ov.w = xv.w * cv.w * g;
            o4[i] = ov;
        }
    }
}

extern "C" void kernel_launch(void* const* d_in, const int* in_sizes, int n_in,
                              void* d_out, int out_size, void* d_ws, size_t ws_size,
                              hipStream_t stream) {
    (void)in_sizes; (void)n_in; (void)ws_size; (void)out_size;
    const float* x    = (const float*)d_in[0];
    const float* g_w  = (const float*)d_in[1];
    const float* l_w  = (const float*)d_in[2];
    const float* w3   = (const float*)d_in[3];
    const float* b3   = (const float*)d_in[4];
    const float* w5   = (const float*)d_in[5];
    const float* b5   = (const float*)d_in[6];
    const float* cw   = (const float*)d_in[7];
    const float* cb   = (const float*)d_in[8];
    const float* sw   = (const float*)d_in[9];
    const float* sb   = (const float*)d_in[10];
    const float* ssc  = (const float*)d_in[11];
    const float* sbi  = (const float*)d_in[12];
    float* outp = (float*)d_out;
    unsigned short* ws = (unsigned short*)d_ws;

    cvt_weights<<<dim3(512), dim3(256), 0, stream>>>(l_w, w3, w5, g_w, cw, ws);
    mafn_fused<<<dim3(B_), dim3(512), 0, stream>>>(
        x, b3, b5, cb, sw, sb, ssc, sbi, ws, outp);
}